// Round 7
// baseline (142.939 us; speedup 1.0000x reference)
//
#include <hip/hip_runtime.h>
#include <math.h>

#define BATCH 8
#define S 512
#define SS (S * S)          // 262144
#define KMAX 16
#define EMPTY_DD 361.1f     // EMPTY_DIST - distance_thre(=1)
#define SENT 1e9f
#define NBLK 512            // 64 blocks/image, 8 rows/block, 2 rows/wave
#define IMB 64
#define RPB 8
#define MAGIC1 0x5A5A0000
#define MAGIC2 0x3C3C3C3C
#define SPIN_MAX (1 << 22)

// ws int layout (no init needed — flags are magic-tagged):
// [0..512)        flag1[blk] = MAGIC1 | local_point_count
// [512..8704)     g_pts[blk*16 + k] : packed pixel idx (y*512+x)
// f[8704..9216)   per-block partial lsum
// f[9216..9728)   per-block partial gsum
// f[9728..10240)  per-block partial lmax
// [10240..10752)  flag2[blk] = MAGIC2

__global__ __launch_bounds__(256, 2) void k_all(const float* __restrict__ pred,
                                                const float* __restrict__ ptl,
                                                const float* __restrict__ ori,
                                                int* __restrict__ wsi,
                                                float* __restrict__ out) {
    float* wsf = (float*)wsi;
    int tid = threadIdx.x;
    int blk = blockIdx.x;
    int b  = blk >> 6;           // image
    int rg = blk & 63;           // row-group (8 rows)
    int wave = tid >> 6;
    int lane = tid & 63;

    __shared__ int l_cnt;
    __shared__ int l_fnd[16];
    __shared__ int l_list[16];
    __shared__ int l_total;
    __shared__ float sm[4][3];
    __shared__ float fin[8][3];

    if (tid == 0) l_cnt = 0;
    __syncthreads();

    // ---- phase A: scan own 8 rows of pt_label ----
    {
        int rowbase = rg * (RPB * S);
        const float4* p4 = (const float4*)(ptl + b * SS + rowbase) + tid * 4;
#pragma unroll
        for (int q = 0; q < 4; q++) {
            float4 v = p4[q];
            float s = v.x + v.y + v.z + v.w;   // labels >= 0
            if (s != 0.0f) {
                int i0 = rowbase + tid * 16 + q * 4;
                float c[4] = {v.x, v.y, v.z, v.w};
#pragma unroll
                for (int j = 0; j < 4; j++) {
                    if (c[j] != 0.0f) {
                        int slot = atomicAdd(&l_cnt, 1);
                        if (slot < 16) l_fnd[slot] = i0 + j;
                    }
                }
            }
        }
    }
    __syncthreads();
    int lcnt = l_cnt; if (lcnt > 16) lcnt = 16;
    if (tid < lcnt) wsi[512 + blk * 16 + tid] = l_fnd[tid];
    __threadfence();
    __syncthreads();
    if (tid == 0) {
        __threadfence();
        __hip_atomic_store(&wsi[blk], MAGIC1 | lcnt,
                           __ATOMIC_RELEASE, __HIP_MEMORY_SCOPE_AGENT);
    }

    // ---- phase B: gradient for own 2 rows (independent of points!) ----
    int yb = rg * RPB + wave * 2;        // wave-uniform; rows yb, yb+1
    int x0 = lane << 3;
    const float* pb = pred + b * SS;
    const float* ob = ori + b * SS;
    float gsum = 0.0f;
    float4 pm[2][2];                      // retained pred rows yb, yb+1

    {
        float q[4][10];
#pragma unroll
        for (int rr = 0; rr < 4; rr++) {
            int yy = yb - 1 + rr;
            if (yy < 0) yy = 0;
            if (yy > S - 1) yy = S - 1;   // clamped rows only feed skipped gradient rows
            const float4* pr  = (const float4*)(pb + yy * S + x0);
            const float4* orr = (const float4*)(ob + yy * S + x0);
            float4 p0 = pr[0], p1 = pr[1];
            float4 o0 = orr[0], o1 = orr[1];
            if (rr == 1) { pm[0][0] = p0; pm[0][1] = p1; }
            if (rr == 2) { pm[1][0] = p0; pm[1][1] = p1; }
            q[rr][1] = p0.x * o0.x; q[rr][2] = p0.y * o0.y;
            q[rr][3] = p0.z * o0.z; q[rr][4] = p0.w * o0.w;
            q[rr][5] = p1.x * o1.x; q[rr][6] = p1.y * o1.y;
            q[rr][7] = p1.z * o1.z; q[rr][8] = p1.w * o1.w;
            q[rr][0] = __shfl_up(q[rr][8], 1, 64);    // lane0 halo dead (x=0 zeroed)
            q[rr][9] = __shfl_down(q[rr][1], 1, 64);  // lane63 halo dead (x=511 zeroed)
        }
#pragma unroll
        for (int it = 0; it < 2; it++) {
            int y = yb + it;
            if (y == 0 || y == S - 1) continue;   // wave-uniform branch
#pragma unroll
            for (int j = 0; j < 8; j++) {
                float a00 = q[it][j],     a01 = q[it][j + 1],     a02 = q[it][j + 2];
                float a10 = q[it + 1][j],                         a12 = q[it + 1][j + 2];
                float a20 = q[it + 2][j], a21 = q[it + 2][j + 1], a22 = q[it + 2][j + 2];
                float g0 = -a00 + a02 - 2.0f * a10 + 2.0f * a12 - a20 + a22;
                float g1 =  a00 + 2.0f * a01 + a02 - a20 - 2.0f * a21 - a22;
                float g2 =  2.0f * a00 + a01 + a10 - a12 - a21 - 2.0f * a22;
                float g3 =  a01 + 2.0f * a02 - a10 + a12 - 2.0f * a20 - a21;
                float gv = fmaxf(fmaxf(fabsf(g0), fabsf(g1)), fmaxf(fabsf(g2), fabsf(g3)));
                bool edge = (lane == 0 && j == 0) || (lane == 63 && j == 7);
                gsum += edge ? 0.0f : gv;
            }
        }
    }

    // ---- per-image point barrier (likely already satisfied) ----
    {
        bool ok = (tid >= IMB);
        for (int g = 0; g < SPIN_MAX; g++) {
            if (!ok) {
                int v = __hip_atomic_load(&wsi[(b << 6) + tid],
                                          __ATOMIC_RELAXED, __HIP_MEMORY_SCOPE_AGENT);
                ok = ((v & 0xFFFF0000) == MAGIC1);
            }
            if (__syncthreads_and(ok)) break;
        }
    }

    // ---- gather this image's points (wave 0, 64 lanes = 64 blocks) ----
    if (wave == 0) {
        int v = __hip_atomic_load(&wsi[(b << 6) + lane],
                                  __ATOMIC_RELAXED, __HIP_MEMORY_SCOPE_AGENT);
        int cj = v & 0xFFFF;
        int pre = cj;
#pragma unroll
        for (int d = 1; d < 64; d <<= 1) {
            int t = __shfl_up(pre, d, 64);
            if (lane >= d) pre += t;
        }
        if (lane == 63) l_total = (pre > 16) ? 16 : pre;
        int off = pre - cj;   // exclusive prefix
        for (int k = 0; k < cj; k++) {
            if (off + k < 16)
                l_list[off + k] = __hip_atomic_load(
                    &wsi[512 + ((b << 6) + lane) * 16 + k],
                    __ATOMIC_RELAXED, __HIP_MEMORY_SCOPE_AGENT);
        }
    }
    __syncthreads();

    int cnt = l_total;
    bool has = cnt > 0;
    float pyk[KMAX], pxk[KMAX];
#pragma unroll
    for (int k = 0; k < KMAX; k++) {
        if (k < cnt) {
            int pk = l_list[k];
            pyk[k] = (float)(pk >> 9);
            pxk[k] = (float)(pk & 511);
        } else { pyk[k] = SENT; pxk[k] = SENT; }
    }

    // ---- phase C: distance term for rows yb, yb+1 (pred rows in regs) ----
    float fx = (float)x0;
    float lsum = 0.0f, lmax = 0.0f;
#pragma unroll
    for (int it = 0; it < 2; it++) {
        float fy = (float)(yb + it);
        float m[8];
#pragma unroll
        for (int j = 0; j < 8; j++) m[j] = 1e30f;
#pragma unroll
        for (int k = 0; k < KMAX; k++) {
            float dy = fy - pyk[k];
            float dy2 = dy * dy;
            float dx = fx - pxk[k];
#pragma unroll
            for (int j = 0; j < 8; j++) {
                float d = dx + (float)j;
                m[j] = fminf(m[j], fmaf(d, d, dy2));
            }
        }
        float dd[8];
#pragma unroll
        for (int j = 0; j < 8; j++)
            dd[j] = has ? fmaxf(sqrtf(m[j]) - 1.0f, 0.0f) : EMPTY_DD;

        float4 pA = pm[it][0], pB = pm[it][1];
        lsum += pA.x * dd[0] + pA.y * dd[1] + pA.z * dd[2] + pA.w * dd[3] +
                pB.x * dd[4] + pB.y * dd[5] + pB.z * dd[6] + pB.w * dd[7];
        float rmax = fmaxf(fmaxf(fmaxf(dd[0], dd[1]), fmaxf(dd[2], dd[3])),
                           fmaxf(fmaxf(dd[4], dd[5]), fmaxf(dd[6], dd[7])));
        lmax = fmaxf(lmax, rmax);
    }

    // ---- block reduce + publish partials ----
#pragma unroll
    for (int off = 32; off > 0; off >>= 1) {
        lsum += __shfl_down(lsum, off, 64);
        gsum += __shfl_down(gsum, off, 64);
        lmax = fmaxf(lmax, __shfl_down(lmax, off, 64));
    }
    if (lane == 0) { sm[wave][0] = lsum; sm[wave][1] = gsum; sm[wave][2] = lmax; }
    __syncthreads();
    if (tid == 0) {
#pragma unroll
        for (int w = 1; w < 4; w++) {
            lsum += sm[w][0];
            gsum += sm[w][1];
            lmax = fmaxf(lmax, sm[w][2]);
        }
        wsf[8704 + blk] = lsum;
        wsf[9216 + blk] = gsum;
        wsf[9728 + blk] = lmax;
        __threadfence();
        __hip_atomic_store(&wsi[10240 + blk], MAGIC2,
                           __ATOMIC_RELEASE, __HIP_MEMORY_SCOPE_AGENT);
    }

    // ---- block 0: wait for all partials, finalize ----
    if (blk == 0) {
        bool ok = false;
        for (int g = 0; g < SPIN_MAX; g++) {
            if (!ok) {
                int v1 = __hip_atomic_load(&wsi[10240 + tid],
                                           __ATOMIC_RELAXED, __HIP_MEMORY_SCOPE_AGENT);
                int v2 = __hip_atomic_load(&wsi[10240 + 256 + tid],
                                           __ATOMIC_RELAXED, __HIP_MEMORY_SCOPE_AGENT);
                ok = (v1 == MAGIC2) && (v2 == MAGIC2);
            }
            if (__syncthreads_and(ok)) break;
        }
        __threadfence();
        // wave w reduces images w and w+4 (64 partials each, one per lane)
#pragma unroll
        for (int pass = 0; pass < 2; pass++) {
            int img = wave + pass * 4;
            int o = img * 64 + lane;
            float ls = __hip_atomic_load(&wsf[8704 + o], __ATOMIC_RELAXED, __HIP_MEMORY_SCOPE_AGENT);
            float gs = __hip_atomic_load(&wsf[9216 + o], __ATOMIC_RELAXED, __HIP_MEMORY_SCOPE_AGENT);
            float lm = __hip_atomic_load(&wsf[9728 + o], __ATOMIC_RELAXED, __HIP_MEMORY_SCOPE_AGENT);
#pragma unroll
            for (int off = 32; off > 0; off >>= 1) {
                ls += __shfl_down(ls, off, 64);
                gs += __shfl_down(gs, off, 64);
                lm = fmaxf(lm, __shfl_down(lm, off, 64));
            }
            if (lane == 0) { fin[img][0] = ls; fin[img][1] = gs; fin[img][2] = lm; }
        }
        __syncthreads();
        if (tid == 0) {
            float dl = 0.0f, gl = 0.0f;
#pragma unroll
            for (int bb = 0; bb < BATCH; bb++) {
                dl += fin[bb][0] / fin[bb][2];
                gl += fin[bb][1];
            }
            out[0] = dl / (float)(SS * BATCH);
            out[1] = gl / (float)(SS * BATCH);
        }
    }
}

extern "C" void kernel_launch(void* const* d_in, const int* in_sizes, int n_in,
                              void* d_out, int out_size, void* d_ws, size_t ws_size,
                              hipStream_t stream) {
    const float* pred = (const float*)d_in[0];
    const float* ptl  = (const float*)d_in[1];
    const float* ori  = (const float*)d_in[2];
    float* out = (float*)d_out;
    int* wsi = (int*)d_ws;

    k_all<<<NBLK, 256, 0, stream>>>(pred, ptl, ori, wsi, out);
}